// Round 4
// baseline (496.545 us; speedup 1.0000x reference)
//
#include <hip/hip_runtime.h>
#include <hip/hip_fp16.h>
#include <math.h>

typedef _Float16 half_t;
typedef _Float16 half8 __attribute__((ext_vector_type(8)));
typedef float f32x4 __attribute__((ext_vector_type(4)));

#define MFMA(a, b, c) __builtin_amdgcn_mfma_f32_16x16x32_f16((a), (b), (c), 0, 0, 0)
// LDS-only barrier: waits lgkmcnt (LDS) but leaves global (vmcnt) prefetch loads
// in flight. Legal: all cross-wave data flows through LDS; 'out' is never re-read.
#define BARRIER() asm volatile("s_waitcnt lgkmcnt(0)\n\ts_barrier" ::: "memory")

static constexpr float kScale = 0.2041241452319315f;  // 24^-0.5
static constexpr int RS   = 104;  // hn / xn / rbuf row stride (halves)
static constexpr int QSTR = 200;  // qbuf row stride (Q|K -> O)
static constexpr int VTS  = 72;   // vT row stride (pbuf aliases per-head slice)
static constexpr int H1S  = 392;  // h1 half row stride

struct W3 { half8 b0, b1, b2; float bias; };

__device__ __forceinline__ W3 ld_w3(const half_t* w, const float* bv, int n0, int qo) {
  W3 r;
  const half_t* wp = w + (size_t)n0 * 96 + qo;
  r.b0 = *(const half8*)(wp);
  r.b1 = *(const half8*)(wp + 32);
  r.b2 = *(const half8*)(wp + 64);
  r.bias = bv[n0];
  return r;
}

__device__ __forceinline__ void qkv_tile(const W3& w, int t, int l15, int quad,
                                         const half8 (&af)[4][3],
                                         half_t* qbuf, half_t* vT) {
  f32x4 acc[4] = {{0,0,0,0},{0,0,0,0},{0,0,0,0},{0,0,0,0}};
#pragma unroll
  for (int g = 0; g < 4; ++g) acc[g] = MFMA(af[g][0], w.b0, acc[g]);
#pragma unroll
  for (int g = 0; g < 4; ++g) acc[g] = MFMA(af[g][1], w.b1, acc[g]);
#pragma unroll
  for (int g = 0; g < 4; ++g) acc[g] = MFMA(af[g][2], w.b2, acc[g]);
  int n0 = t * 16 + l15;
  if (t < 12) {                      // Q (scaled) and K -> qbuf col n0
    float sc_ = (t < 6) ? kScale : 1.f;
#pragma unroll
    for (int g = 0; g < 4; ++g)
#pragma unroll
      for (int r = 0; r < 4; ++r)
        qbuf[(g * 16 + quad * 4 + r) * QSTR + n0] = (half_t)((acc[g][r] + w.bias) * sc_);
  } else {                           // V -> vT [head][c][token]
    int vc = n0 - 192;
    int hd = vc / 24, c = vc - hd * 24;
#pragma unroll
    for (int g = 0; g < 4; ++g)
#pragma unroll
      for (int r = 0; r < 4; ++r)
        vT[hd * 24 * VTS + c * VTS + g * 16 + quad * 4 + r] = (half_t)(acc[g][r] + w.bias);
  }
}

__device__ __forceinline__ void fc1_tile(const W3& w, int t, int l15, int quad,
                                         const half8 (&a0f)[3], const half8 (&a1f)[3],
                                         half_t* h1h) {
  f32x4 a0 = {0,0,0,0}, a1 = {0,0,0,0};
  a0 = MFMA(a0f[0], w.b0, a0); a1 = MFMA(a1f[0], w.b0, a1);
  a0 = MFMA(a0f[1], w.b1, a0); a1 = MFMA(a1f[1], w.b1, a1);
  a0 = MFMA(a0f[2], w.b2, a0); a1 = MFMA(a1f[2], w.b2, a1);
  int n0 = t * 16 + l15;
#pragma unroll
  for (int g2 = 0; g2 < 2; ++g2) {
    const f32x4& ac = g2 ? a1 : a0;
#pragma unroll
    for (int r = 0; r < 4; ++r) {
      float vvv = ac[r] + w.bias;
      // GELU: v * sigmoid(v*(1.5957691 + 0.14270963*v^2))
      float u = vvv * (1.5957691216f + 0.1427096322f * vvv * vvv);
      float g = vvv * __builtin_amdgcn_rcpf(1.f + __expf(-u));
      h1h[(g2 * 16 + quad * 4 + r) * H1S + n0] = (half_t)g;
    }
  }
}

__device__ __forceinline__ void fc2_ld(const half_t* fc2w, int t, int l15, int qo,
                                       half8 (&bf)[12]) {
#pragma unroll
  for (int kt = 0; kt < 12; ++kt)
    bf[kt] = *(const half8*)(fc2w + (size_t)(t * 16 + l15) * 384 + kt * 32 + qo);
}

__device__ __forceinline__ void fc2_tile(const half8 (&a2)[12], const half8 (&bf)[12],
                                         int t, int hb, int rt, int l15, int quad,
                                         int wh, int ww, int bb,
                                         const float* fc2b, const half_t* rbuf,
                                         float* out) {
  f32x4 acc = {0,0,0,0};
#pragma unroll
  for (int kt = 0; kt < 12; ++kt) acc = MFMA(a2[kt], bf[kt], acc);
  int col = t * 16 + l15;
  float bias = fc2b[col];
#pragma unroll
  for (int r = 0; r < 4; ++r) {
    int tok = hb * 32 + rt * 16 + quad * 4 + r;
    int sr = (wh * 8 + (tok >> 3) + 4) & 63;
    int sc = (ww * 8 + (tok & 7) + 4) & 63;
    out[((size_t)bb * 4096 + sr * 64 + sc) * 96 + col] = (float)rbuf[tok * RS + col] + acc[r] + bias;
  }
}

// BASE selects which half of a5b; LOADF1: issue own f1A/f1B at entry (hb=1 pass).
template <int BASE, bool LOADF1>
__device__ __forceinline__ void p5_pass(const half8 (&a5b)[4][3], int wave, int l15,
                                        int quad, int qo, int chh, half_t* h1h,
                                        const half_t* fc1w, const float* fc1b,
                                        const half_t* fc2w,
                                        W3& f1A, W3& f1B, half8 (&bfA)[12]) {
  if (LOADF1) {
    f1A = ld_w3(fc1w, fc1b, wave * 16 + l15, qo);
    f1B = ld_w3(fc1w, fc1b, (wave + 4) * 16 + l15, qo);
  }
  fc1_tile(f1A, wave, l15, quad, a5b[BASE], a5b[BASE + 1], h1h);
  f1A = ld_w3(fc1w, fc1b, (wave + 8) * 16 + l15, qo);
  fc1_tile(f1B, wave + 4, l15, quad, a5b[BASE], a5b[BASE + 1], h1h);
  f1B = ld_w3(fc1w, fc1b, (wave + 12) * 16 + l15, qo);
  fc1_tile(f1A, wave + 8, l15, quad, a5b[BASE], a5b[BASE + 1], h1h);
  f1A = ld_w3(fc1w, fc1b, (wave + 16) * 16 + l15, qo);
  fc1_tile(f1B, wave + 12, l15, quad, a5b[BASE], a5b[BASE + 1], h1h);
  f1B = ld_w3(fc1w, fc1b, (wave + 20) * 16 + l15, qo);
  fc1_tile(f1A, wave + 16, l15, quad, a5b[BASE], a5b[BASE + 1], h1h);
  fc2_ld(fc2w, chh * 3 + 0, l15, qo, bfA);   // prefetch fc2 tile 0 for P6
  fc1_tile(f1B, wave + 20, l15, quad, a5b[BASE], a5b[BASE + 1], h1h);
}

__device__ __forceinline__ void p6_pass(int hb, int wave, int l15, int quad, int qo, int chh,
                                        int wh, int ww, int bb,
                                        const half_t* h1h, const half_t* rbuf,
                                        const half_t* fc2w, const float* fc2b,
                                        float* out, half8 (&bfA)[12], half8 (&bfB)[12]) {
  int rt = wave >> 1;
  half8 a2[12];
#pragma unroll
  for (int kt = 0; kt < 12; ++kt)
    a2[kt] = *(const half8*)(&h1h[(rt * 16 + l15) * H1S + kt * 32 + qo]);
  fc2_ld(fc2w, chh * 3 + 1, l15, qo, bfB);
  fc2_tile(a2, bfA, chh * 3 + 0, hb, rt, l15, quad, wh, ww, bb, fc2b, rbuf, out);
  fc2_ld(fc2w, chh * 3 + 2, l15, qo, bfA);
  fc2_tile(a2, bfB, chh * 3 + 1, hb, rt, l15, quad, wh, ww, bb, fc2b, rbuf, out);
  fc2_tile(a2, bfA, chh * 3 + 2, hb, rt, l15, quad, wh, ww, bb, fc2b, rbuf, out);
}

// ---- weights -> fp16, plus rel-pos bias expanded to [head][i][j] fp32 (64 KB)
__global__ __launch_bounds__(256) void k_convert(const float* __restrict__ qkv_w,
                                                 const float* __restrict__ proj_w,
                                                 const float* __restrict__ fc1_w,
                                                 const float* __restrict__ fc2_w,
                                                 const float* __restrict__ tbl,
                                                 half_t* __restrict__ wbuf,
                                                 float* __restrict__ biasT) {
  int i = blockIdx.x * 256 + threadIdx.x;
  if (i < 27648)        wbuf[i] = (half_t)qkv_w[i];
  else if (i < 36864)   wbuf[i] = (half_t)proj_w[i - 27648];
  else if (i < 73728)   wbuf[i] = (half_t)fc1_w[i - 36864];
  else if (i < 110592)  wbuf[i] = (half_t)fc2_w[i - 73728];
  else if (biasT != nullptr) {
    int j = i - 110592;                  // [head][i][j] : 4 * 64 * 64
    int h = j >> 12, rem = j & 4095;
    int ii = rem >> 6, jj = rem & 63;
    int ih = ii >> 3, iw = ii & 7, jh = jj >> 3, jw = jj & 7;
    biasT[j] = tbl[((ih - jh + 7) * 15 + (iw - jw + 7)) * 4 + h];
  }
}

// ===== whole Swin block fused; block-shared B tiles, LDS-only barriers, deep
// register prefetch. LDS peak 39424 (hn overlaid by qbuf after af-read barrier)
// -> 4 blocks/CU (16 waves). smem padded to 40960 for the benign head-3 vT
// over-read (contaminates only discarded O lanes 24..31).
// Map:  hn@0 (P0) -> qbuf@0 25600 + vT@25600 13824 (P1-P2)
//       -> rbuf@0 13312 + xn@13312 13312 (D) -> h1h@13312 25088 (MLP, over xn)
__global__ __launch_bounds__(256, 4) void k_swin(
    const float* __restrict__ x,
    const float* __restrict__ n1g, const float* __restrict__ n1b,
    const half_t* __restrict__ qkvw, const float* __restrict__ qkv_b,
    const float* __restrict__ tbl_g, const float* __restrict__ biasT,
    const half_t* __restrict__ projw, const float* __restrict__ proj_b,
    const float* __restrict__ n2g, const float* __restrict__ n2b,
    const half_t* __restrict__ fc1w, const float* __restrict__ fc1b,
    const half_t* __restrict__ fc2w, const float* __restrict__ fc2b,
    float* __restrict__ out) {
  __shared__ __attribute__((aligned(16))) unsigned char smem[40960];
  half_t* hn   = (half_t*)smem;
  half_t* qbuf = (half_t*)smem;
  half_t* vT   = (half_t*)(smem + 25600);
  half_t* rbuf = (half_t*)smem;
  half_t* xn   = (half_t*)(smem + 13312);
  half_t* h1h  = (half_t*)(smem + 13312);

  int tid = threadIdx.x;
  int wave = tid >> 6, lane = tid & 63;
  int l15 = lane & 15, quad = lane >> 4;
  int qo = quad * 8, chh = wave & 1;
  int blk = blockIdx.x;                        // bb*64 + wh*8 + ww
  int bb = blk >> 6, wh = (blk >> 3) & 7, ww = blk & 7;

  // ---- P0: LN1 (x loads issued first; first two QKV weight tiles prefetched)
  float v[24];
  {
    int tok = wave * 16 + l15;
    int sr = (wh * 8 + (tok >> 3) + 4) & 63;
    int sc = (ww * 8 + (tok & 7) + 4) & 63;
    const float* rp = x + ((size_t)bb * 4096 + sr * 64 + sc) * 96;
#pragma unroll
    for (int kt = 0; kt < 3; ++kt) {
      float4 a = *(const float4*)(rp + kt * 32 + qo);
      float4 b = *(const float4*)(rp + kt * 32 + qo + 4);
      v[kt*8+0]=a.x; v[kt*8+1]=a.y; v[kt*8+2]=a.z; v[kt*8+3]=a.w;
      v[kt*8+4]=b.x; v[kt*8+5]=b.y; v[kt*8+6]=b.z; v[kt*8+7]=b.w;
    }
  }
  W3 qA = ld_w3(qkvw, qkv_b, wave * 16 + l15, qo);
  W3 qB = ld_w3(qkvw, qkv_b, (wave + 4) * 16 + l15, qo);
  {
    int tok = wave * 16 + l15;
    float s1 = 0.f, s2 = 0.f;
#pragma unroll
    for (int c = 0; c < 24; ++c) { s1 += v[c]; s2 += v[c] * v[c]; }
    s1 += __shfl_xor(s1, 16); s1 += __shfl_xor(s1, 32);
    s2 += __shfl_xor(s2, 16); s2 += __shfl_xor(s2, 32);
    float mu = s1 * (1.f / 96.f);
    float inv = rsqrtf(fmaxf(s2 * (1.f / 96.f) - mu * mu, 0.f) + 1e-5f);
#pragma unroll
    for (int kt = 0; kt < 3; ++kt) {
      int c0 = kt * 32 + qo;
      float4 g0 = *(const float4*)(n1g + c0);
      float4 g1 = *(const float4*)(n1g + c0 + 4);
      float4 b0 = *(const float4*)(n1b + c0);
      float4 b1 = *(const float4*)(n1b + c0 + 4);
      float gg[8] = {g0.x,g0.y,g0.z,g0.w,g1.x,g1.y,g1.z,g1.w};
      float bv[8] = {b0.x,b0.y,b0.z,b0.w,b1.x,b1.y,b1.z,b1.w};
      half8 hh;
#pragma unroll
      for (int j = 0; j < 8; ++j)
        hh[j] = (half_t)((v[kt*8+j] - mu) * inv * gg[j] + bv[j]);
      *(half8*)(&hn[tok * RS + kt * 32 + qo]) = hh;
    }
  }
  BARRIER();  // B0: hn visible

  // ---- P1pre: every wave pulls all A-fragments; then hn is dead
  W3 qC = ld_w3(qkvw, qkv_b, (wave + 8) * 16 + l15, qo);
  half8 af[4][3];
#pragma unroll
  for (int g = 0; g < 4; ++g)
#pragma unroll
    for (int kt = 0; kt < 3; ++kt)
      af[g][kt] = *(const half8*)(&hn[(g * 16 + l15) * RS + kt * 32 + qo]);
  BARRIER();  // B0b: hn consumed -> qbuf may overlay it

  // ---- P1: QKV GEMM, column-split, 2-deep weight pipeline
  {
    qkv_tile(qA, wave, l15, quad, af, qbuf, vT);
    qA = ld_w3(qkvw, qkv_b, (wave + 12) * 16 + l15, qo);
    qkv_tile(qB, wave + 4, l15, quad, af, qbuf, vT);
    if (wave < 2) qB = ld_w3(qkvw, qkv_b, (wave + 16) * 16 + l15, qo);
    qkv_tile(qC, wave + 8, l15, quad, af, qbuf, vT);
    qkv_tile(qA, wave + 12, l15, quad, af, qbuf, vT);
    if (wave < 2) qkv_tile(qB, wave + 16, l15, quad, af, qbuf, vT);
  }
  // prefetch this head's rel-pos bias (64 floats) across B1
  int head = wave;
  float bt[4][16];
  if (biasT != nullptr) {
#pragma unroll
    for (int g2 = 0; g2 < 4; ++g2)
#pragma unroll
      for (int r = 0; r < 4; ++r) {
        const float* bp = biasT + (head << 12) + ((g2 * 16 + quad * 4 + r) << 6) + l15;
#pragma unroll
        for (int nt = 0; nt < 4; ++nt) bt[g2][r * 4 + nt] = bp[nt * 16];
      }
  }
  BARRIER();  // B1: Q,K,V staged

  // ---- P2: attention, wave = head
  {
    const half8 z8 = {};
    half8 kb[4], vb[2][2];
#pragma unroll
    for (int nt = 0; nt < 4; ++nt) {
      half8 t = *(const half8*)(&qbuf[(nt * 16 + l15) * QSTR + 96 + head * 24 + qo]);
      kb[nt] = (quad < 3) ? t : z8;
    }
#pragma unroll
    for (int nt = 0; nt < 2; ++nt)
#pragma unroll
      for (int kt = 0; kt < 2; ++kt)
        vb[nt][kt] = *(const half8*)(&vT[head * 24 * VTS + (nt * 16 + l15) * VTS + kt * 32 + qo]);

    int rj[4], jh_[4], jw_[4];
#pragma unroll
    for (int nt = 0; nt < 4; ++nt) {
      int j = nt * 16 + l15;
      jh_[nt] = j >> 3; jw_[nt] = j & 7;
      int rr = wh * 8 + jh_[nt], cc = ww * 8 + jw_[nt];
      rj[nt] = ((rr < 56) ? 0 : ((rr < 60) ? 1 : 2)) * 3 + ((cc < 56) ? 0 : ((cc < 60) ? 1 : 2));
    }

    half_t* pb = vT + head * 24 * VTS;   // wave-private alias over own vT slice
    f32x4 oacc[4][2];

#pragma unroll
    for (int g2 = 0; g2 < 4; ++g2) {
      half8 qt = *(const half8*)(&qbuf[(g2 * 16 + l15) * QSTR + head * 24 + qo]);
      half8 qa = (quad < 3) ? qt : z8;
      f32x4 sv[4];
#pragma unroll
      for (int nt = 0; nt < 4; ++nt) {
        f32x4 a = {0, 0, 0, 0};
        sv[nt] = MFMA(qa, kb[nt], a);
      }
      float pinv[4];
#pragma unroll
      for (int r = 0; r < 4; ++r) {
        int i = g2 * 16 + quad * 4 + r;
        int ih = i >> 3, iw = i & 7;
        int rr = wh * 8 + ih, cc = ww * 8 + iw;
        int ri = ((rr < 56) ? 0 : ((rr < 60) ? 1 : 2)) * 3 + ((cc < 56) ? 0 : ((cc < 60) ? 1 : 2));
#pragma unroll
        for (int nt = 0; nt < 4; ++nt) {
          float bvv;
          if (biasT != nullptr) bvv = bt[g2][r * 4 + nt];
          else bvv = tbl_g[((ih - jh_[nt] + 7) * 15 + (iw - jw_[nt] + 7)) * 4 + head];
          float val = sv[nt][r] + bvv;
          if (ri != rj[nt]) val -= 100.f;
          sv[nt][r] = val;
        }
        float mx = fmaxf(fmaxf(sv[0][r], sv[1][r]), fmaxf(sv[2][r], sv[3][r]));
        mx = fmaxf(mx, __shfl_xor(mx, 1));
        mx = fmaxf(mx, __shfl_xor(mx, 2));
        mx = fmaxf(mx, __shfl_xor(mx, 4));
        mx = fmaxf(mx, __shfl_xor(mx, 8));
        float sum = 0.f;
#pragma unroll
        for (int nt = 0; nt < 4; ++nt) {
          float e = __expf(sv[nt][r] - mx);
          sv[nt][r] = e;
          sum += e;
        }
        sum += __shfl_xor(sum, 1);
        sum += __shfl_xor(sum, 2);
        sum += __shfl_xor(sum, 4);
        sum += __shfl_xor(sum, 8);
        pinv[r] = __builtin_amdgcn_rcpf(sum);
      }
#pragma unroll
      for (int nt = 0; nt < 4; ++nt)
#pragma unroll
        for (int r = 0; r < 4; ++r)
          pb[(quad * 4 + r) * VTS + nt * 16 + l15] = (half_t)(sv[nt][r] * pinv[r]);
      __builtin_amdgcn_sched_barrier(0);
      half8 pa0 = *(const half8*)(&pb[l15 * VTS + qo]);
      half8 pa1 = *(const half8*)(&pb[l15 * VTS + 32 + qo]);
#pragma unroll
      for (int nt = 0; nt < 2; ++nt) {
        f32x4 a = {0, 0, 0, 0};
        a = MFMA(pa0, vb[nt][0], a);
        a = MFMA(pa1, vb[nt][1], a);
        oacc[g2][nt] = a;
      }
    }
    // O -> qbuf over own head's Q columns (intra-wave in-order; no barrier needed)
#pragma unroll
    for (int g2 = 0; g2 < 4; ++g2)
#pragma unroll
      for (int nt = 0; nt < 2; ++nt) {
        int c = nt * 16 + l15;
        if (c < 24)
#pragma unroll
          for (int r = 0; r < 4; ++r)
            qbuf[(g2 * 16 + quad * 4 + r) * QSTR + head * 24 + c] = (half_t)oacc[g2][nt][r];
      }
  }
  // prefetch across B2: all 6 proj tiles, residual x, LN2 gamma/beta
  W3 pw[6];
#pragma unroll
  for (int t = 0; t < 6; ++t) pw[t] = ld_w3(projw, proj_b, t * 16 + l15, qo);
  float xv[6][4];
#pragma unroll
  for (int r = 0; r < 4; ++r) {
    int tok2 = wave * 16 + quad * 4 + r;
    int sr = (wh * 8 + (tok2 >> 3) + 4) & 63;
    int sc = (ww * 8 + (tok2 & 7) + 4) & 63;
    const float* xp = x + ((size_t)bb * 4096 + sr * 64 + sc) * 96 + l15;
#pragma unroll
    for (int t = 0; t < 6; ++t) xv[t][r] = xp[t * 16];
  }
  float gn2[6], bn2[6];
#pragma unroll
  for (int t = 0; t < 6; ++t) { gn2[t] = n2g[t * 16 + l15]; bn2[t] = n2b[t * 16 + l15]; }
  BARRIER();  // B2: all heads' O columns visible

  // ---- D: proj (row-split) + residual + LN2 fused -> rbuf@0 + xn@13312
  {
    half8 oa[3];
#pragma unroll
    for (int kt = 0; kt < 3; ++kt)
      oa[kt] = *(const half8*)(&qbuf[(wave * 16 + l15) * QSTR + kt * 32 + qo]);
    BARRIER();  // B2b: qbuf fully consumed -> rbuf/xn may overlay it
    f32x4 acc[6];
#pragma unroll
    for (int t = 0; t < 6; ++t) {
      f32x4 a = {0, 0, 0, 0};
      a = MFMA(oa[0], pw[t].b0, a);
      a = MFMA(oa[1], pw[t].b1, a);
      a = MFMA(oa[2], pw[t].b2, a);
      acc[t] = a;
    }
    float rv[6][4];
    float s1[4] = {0, 0, 0, 0}, s2[4] = {0, 0, 0, 0};
#pragma unroll
    for (int t = 0; t < 6; ++t)
#pragma unroll
      for (int r = 0; r < 4; ++r) {
        float vvv = xv[t][r] + acc[t][r] + pw[t].bias;
        rv[t][r] = vvv;
        s1[r] += vvv; s2[r] += vvv * vvv;
      }
    float mu[4], nv[4];
#pragma unroll
    for (int r = 0; r < 4; ++r) {
      s1[r] += __shfl_xor(s1[r], 1); s1[r] += __shfl_xor(s1[r], 2);
      s1[r] += __shfl_xor(s1[r], 4); s1[r] += __shfl_xor(s1[r], 8);
      s2[r] += __shfl_xor(s2[r], 1); s2[r] += __shfl_xor(s2[r], 2);
      s2[r] += __shfl_xor(s2[r], 4); s2[r] += __shfl_xor(s2[r], 8);
      mu[r] = s1[r] * (1.f / 96.f);
      nv[r] = rsqrtf(fmaxf(s2[r] * (1.f / 96.f) - mu[r] * mu[r], 0.f) + 1e-5f);
    }
#pragma unroll
    for (int t = 0; t < 6; ++t) {
      int n0 = t * 16 + l15;
#pragma unroll
      for (int r = 0; r < 4; ++r) {
        int row = wave * 16 + quad * 4 + r;
        rbuf[row * RS + n0] = (half_t)rv[t][r];
        xn[row * RS + n0] = (half_t)((rv[t][r] - mu[r]) * nv[r] * gn2[t] + bn2[t]);
      }
    }
  }
  // prefetch first two fc1 tiles across B3
  W3 f1A = ld_w3(fc1w, fc1b, wave * 16 + l15, qo);
  W3 f1B = ld_w3(fc1w, fc1b, (wave + 4) * 16 + l15, qo);
  half8 bfA[12], bfB[12];
  BARRIER();  // B3: xn + rbuf ready

  // ---- MLP prelude: pull BOTH halves' A-fragments; then xn is dead
  half8 a5b[4][3];
#pragma unroll
  for (int g = 0; g < 4; ++g)
#pragma unroll
    for (int kt = 0; kt < 3; ++kt)
      a5b[g][kt] = *(const half8*)(&xn[(g * 16 + l15) * RS + kt * 32 + qo]);
  BARRIER();  // B3b: xn consumed -> h1h may overlay it

  // ---- MLP: two 32-row halves, software-pipelined
  p5_pass<0, false>(a5b, wave, l15, quad, qo, chh, h1h, fc1w, fc1b, fc2w, f1A, f1B, bfA);
  BARRIER();  // B4
  p6_pass(0, wave, l15, quad, qo, chh, wh, ww, bb, h1h, rbuf, fc2w, fc2b, out, bfA, bfB);
  BARRIER();  // B5: h1h consumed -> reuse for hb=1
  p5_pass<2, true>(a5b, wave, l15, quad, qo, chh, h1h, fc1w, fc1b, fc2w, f1A, f1B, bfA);
  BARRIER();  // B6
  p6_pass(1, wave, l15, quad, qo, chh, wh, ww, bb, h1h, rbuf, fc2w, fc2b, out, bfA, bfB);
}

extern "C" void kernel_launch(void* const* d_in, const int* in_sizes, int n_in,
                              void* d_out, int out_size, void* d_ws, size_t ws_size,
                              hipStream_t stream) {
  const float* x      = (const float*)d_in[0];
  const float* n1g    = (const float*)d_in[1];
  const float* n1b    = (const float*)d_in[2];
  const float* qkv_w  = (const float*)d_in[3];
  const float* qkv_b  = (const float*)d_in[4];
  const float* rtbl   = (const float*)d_in[5];
  const float* proj_w = (const float*)d_in[6];
  const float* proj_b = (const float*)d_in[7];
  const float* n2g    = (const float*)d_in[8];
  const float* n2b    = (const float*)d_in[9];
  const float* fc1_w  = (const float*)d_in[10];
  const float* fc1_b  = (const float*)d_in[11];
  const float* fc2_w  = (const float*)d_in[12];
  const float* fc2_b  = (const float*)d_in[13];
  float* out = (float*)d_out;

  if (ws_size < 221184) return;
  half_t* wbuf = (half_t*)d_ws;
  float* biasT = (ws_size >= 221184 + 65536) ? (float*)((char*)d_ws + 221184) : nullptr;

  k_convert<<<496, 256, 0, stream>>>(qkv_w, proj_w, fc1_w, fc2_w, rtbl, wbuf, biasT);
  k_swin<<<4096, 256, 0, stream>>>(x, n1g, n1b, wbuf, qkv_b, rtbl, biasT,
                                   wbuf + 27648, proj_b, n2g, n2b,
                                   wbuf + 36864, fc1_b, wbuf + 73728, fc2_b, out);
}